// Round 7
// baseline (244.969 us; speedup 1.0000x reference)
//
#include <hip/hip_runtime.h>
#include <hip/hip_bf16.h>

#define BB 8
#define SQ 2048
#define SK 2048
#define DD 128
#define INV_TEMPER 0.08838834764831845f  // 1/sqrt(128)

using s16x8 = __attribute__((ext_vector_type(8))) short;
using f32x4 = __attribute__((ext_vector_type(4))) float;
using i32x4 = __attribute__((ext_vector_type(4))) int;

__device__ __forceinline__ unsigned short f2bf(float f) {
  union { float f; unsigned u; } v; v.f = f;
  unsigned r = v.u + 0x7FFFu + ((v.u >> 16) & 1u);
  return (unsigned short)(r >> 16);
}
__device__ __forceinline__ float bf2f(unsigned short h) {
  union { unsigned u; float f; } v; v.u = ((unsigned)h) << 16; return v.f;
}

// K fp32 -> bf16, same layout [b][k][d]
__global__ __launch_bounds__(256) void prep_k_kernel(const float* __restrict__ k,
                                                     unsigned short* __restrict__ kb) {
  const size_t i = ((size_t)blockIdx.x * 256 + threadIdx.x) * 8;
  const float4 a = *(const float4*)(k + i);
  const float4 c = *(const float4*)(k + i + 4);
  ushort4 o0, o1;
  o0.x = f2bf(a.x); o0.y = f2bf(a.y); o0.z = f2bf(a.z); o0.w = f2bf(a.w);
  o1.x = f2bf(c.x); o1.y = f2bf(c.y); o1.z = f2bf(c.z); o1.w = f2bf(c.w);
  *(ushort4*)(kb + i) = o0;
  *(ushort4*)(kb + i + 4) = o1;
}

// V fp32 [b][k][d] -> bf16 V^T [b][d][k]
__global__ __launch_bounds__(256) void prep_v_kernel(const float* __restrict__ v,
                                                     unsigned short* __restrict__ vt) {
  constexpr int TS = 132;
  __shared__ __align__(16) unsigned short tile[64 * TS];
  const int tid = threadIdx.x;
  const int bid = blockIdx.x;
  const int b  = bid >> 5;
  const int k0 = (bid & 31) << 6;
#pragma unroll
  for (int p = 0; p < 8; ++p) {
    const int row = p * 8 + (tid >> 5);
    const int c4  = (tid & 31) << 2;
    const float4 vv = *(const float4*)(v + ((size_t)(b * SK + k0 + row)) * DD + c4);
    ushort4 o; o.x = f2bf(vv.x); o.y = f2bf(vv.y); o.z = f2bf(vv.z); o.w = f2bf(vv.w);
    *(ushort4*)(&tile[row * TS + c4]) = o;
  }
  __syncthreads();
#pragma unroll
  for (int p = 0; p < 8; ++p) {
    const int u = p * 256 + tid;
    const int d  = u >> 4;
    const int kw = (u & 15) << 2;
    ushort4 o;
    o.x = tile[(kw + 0) * TS + d];
    o.y = tile[(kw + 1) * TS + d];
    o.z = tile[(kw + 2) * TS + d];
    o.w = tile[(kw + 3) * TS + d];
    *(ushort4*)(vt + ((size_t)(b * DD + d)) * SK + k0 + kw) = o;
  }
}

// Single-pass fused attention. Per block: 32 q-rows. Per wave: a private 256-k
// slice (no block barriers in the main loop). P (unnormalized exp, bf16) lives
// in a persistent 128KB LDS buffer; O accumulates unnormalized; one epilogue
// normalizes both and streams attn out coalesced+nontemporal.
#define PSTR 2056   // P row stride (ushorts): 4112B = 16B-aligned, 2-way banks max
#define BMS  260    // mask-bit row stride (bytes)

__global__ __launch_bounds__(512, 2) void fused_attn(
    const float* __restrict__ q, const int* __restrict__ mask,
    const unsigned short* __restrict__ kb, const unsigned short* __restrict__ vt,
    float* __restrict__ outp, float* __restrict__ attn) {
  __shared__ __align__(16) unsigned short P[32 * PSTR];  // 131,584 B
  __shared__ unsigned char bm[32 * BMS];                 //   8,320 B
  __shared__ float obuf[32 * 128];                       //  16,384 B
  __shared__ float redl[8][32];                          //   1,024 B
  __shared__ float il_s[32];                             //     128 B

  const int tid = threadIdx.x;
  const int bid = blockIdx.x;
  // 512 blocks = 8 XCD x 64 (bijective): batch pinned to one XCD, kb/vt L2-hot
  const int swz = ((bid & 7) << 6) + (bid >> 3);
  const int b  = swz >> 6;
  const int q0 = (swz & 63) << 5;
  const int lane = tid & 63;
  const int w    = tid >> 6;       // wave 0..7
  const int lrow = lane & 15;
  const int lk   = lane >> 4;
  const int rowb = lk << 2;
  const int slice0 = w << 8;       // this wave's private 256-k slice

  // zero O accumulator buffer
#pragma unroll
  for (int i = 0; i < 8; ++i) obuf[tid + (i << 9)] = 0.0f;

  // ---- mask ingest: nontemporal int4, 1 bit/elem ----
  {
    const int* mbase = mask + ((size_t)(b * SQ + q0)) * SK;
#pragma unroll
    for (int i = 0; i < 16; ++i) {
      const int u = (i << 9) + tid;
      const int grow = u >> 8;
      const int gb   = u & 255;
      const int* pp = mbase + (size_t)grow * SK + ((size_t)gb << 3);
      const i32x4 m0 = __builtin_nontemporal_load((const i32x4*)pp);
      const i32x4 m1 = __builtin_nontemporal_load(((const i32x4*)pp) + 1);
      unsigned bv = (unsigned)(m0.x != 0) | ((unsigned)(m0.y != 0) << 1) |
                    ((unsigned)(m0.z != 0) << 2) | ((unsigned)(m0.w != 0) << 3) |
                    ((unsigned)(m1.x != 0) << 4) | ((unsigned)(m1.y != 0) << 5) |
                    ((unsigned)(m1.z != 0) << 6) | ((unsigned)(m1.w != 0) << 7);
      bm[grow * BMS + gb] = (unsigned char)bv;
    }
  }

  // ---- Q A-fragments (32 rows x 128 d) ----
  s16x8 af0[4], af1[4];
#pragma unroll
  for (int ks = 0; ks < 4; ++ks) {
    const float* qp0 = q + ((size_t)(b * SQ + q0 + lrow)) * DD + ks * 32 + lk * 8;
    const float* qp1 = qp0 + 16 * DD;
    const float4 a0 = *(const float4*)qp0;
    const float4 a1 = *(const float4*)(qp0 + 4);
    const float4 c0 = *(const float4*)qp1;
    const float4 c1 = *(const float4*)(qp1 + 4);
    s16x8 x, y;
    x[0] = (short)f2bf(a0.x); x[1] = (short)f2bf(a0.y); x[2] = (short)f2bf(a0.z); x[3] = (short)f2bf(a0.w);
    x[4] = (short)f2bf(a1.x); x[5] = (short)f2bf(a1.y); x[6] = (short)f2bf(a1.z); x[7] = (short)f2bf(a1.w);
    y[0] = (short)f2bf(c0.x); y[1] = (short)f2bf(c0.y); y[2] = (short)f2bf(c0.z); y[3] = (short)f2bf(c0.w);
    y[4] = (short)f2bf(c1.x); y[5] = (short)f2bf(c1.y); y[6] = (short)f2bf(c1.z); y[7] = (short)f2bf(c1.w);
    af0[ks] = x; af1[ks] = y;
  }

  __syncthreads();  // bm + obuf ready

  // per-wave base pointers into its k-slice
  const unsigned short* kfp = kb + (size_t)b * SK * DD + (size_t)(slice0 + lrow) * DD + lk * 8;
  const unsigned short* vfp = vt + ((size_t)(b * DD + lrow)) * SK + slice0 + lk * 8;

  float ls[8];
#pragma unroll
  for (int i = 0; i < 8; ++i) ls[i] = 0.0f;
  f32x4 oA[8], oB[8];
#pragma unroll
  for (int nt = 0; nt < 8; ++nt) { oA[nt] = f32x4{0.f,0.f,0.f,0.f}; oB[nt] = f32x4{0.f,0.f,0.f,0.f}; }

  // QK^T for one 16-col tile -> exp -> P + lsum (all intra-wave)
  auto qk_sink = [&](int ct, const s16x8* kf) {
    f32x4 a0 = {0.f,0.f,0.f,0.f}, a1 = {0.f,0.f,0.f,0.f};
    __builtin_amdgcn_s_setprio(1);
#pragma unroll
    for (int ks = 0; ks < 4; ++ks) {
      a0 = __builtin_amdgcn_mfma_f32_16x16x32_bf16(af0[ks], kf[ks], a0, 0, 0, 0);
      a1 = __builtin_amdgcn_mfma_f32_16x16x32_bf16(af1[ks], kf[ks], a1, 0, 0, 0);
    }
    __builtin_amdgcn_s_setprio(0);
    const int colg = slice0 + (ct << 4) + lrow;
    const int byb = colg >> 3, bit = colg & 7;
#pragma unroll
    for (int rt = 0; rt < 2; ++rt)
#pragma unroll
      for (int r = 0; r < 4; ++r) {
        const int row = rt * 16 + rowb + r;
        const int live = (bm[row * BMS + byb] >> bit) & 1;
        const float s = (rt ? a1[r] : a0[r]) * INV_TEMPER;
        const float e = live ? __expf(s) : 0.0f;
        ls[rt * 4 + r] += e;
        P[row * PSTR + colg] = f2bf(e);
      }
  };

  s16x8 kA[4], kB[4];
#pragma unroll
  for (int ks = 0; ks < 4; ++ks) kA[ks] = *(const s16x8*)(kfp + ks * 32);  // ct=0

#pragma unroll 1
  for (int kk = 0; kk < 8; ++kk) {
    const int koff = kk << 5;
    // V-frags for this 32-k step (consumed at iteration end; latency hides under QK)
    s16x8 vf[8];
#pragma unroll
    for (int nt = 0; nt < 8; ++nt)
      vf[nt] = *(const s16x8*)(vfp + (size_t)(nt << 4) * SK + koff);
    // K-frags ct = 2kk+1
#pragma unroll
    for (int ks = 0; ks < 4; ++ks)
      kB[ks] = *(const s16x8*)(kfp + (size_t)(((kk << 1) + 1) << 4) * DD + ks * 32);
    qk_sink(kk << 1, kA);
    // prefetch K-frags ct = 2kk+2 (wraps harmlessly on last iter)
#pragma unroll
    for (int ks = 0; ks < 4; ++ks)
      kA[ks] = *(const s16x8*)(kfp + (size_t)((((kk << 1) + 2) & 15) << 4) * DD + ks * 32);
    qk_sink((kk << 1) + 1, kB);
    // own P writes -> own A-frag reads: intra-wave, no barrier
    asm volatile("s_waitcnt lgkmcnt(0)" ::: "memory");
    __builtin_amdgcn_sched_barrier(0);
    const int ko = slice0 + koff + (lk << 3);
    const s16x8 pa0 = *(const s16x8*)(&P[lrow * PSTR + ko]);
    const s16x8 pa1 = *(const s16x8*)(&P[(16 + lrow) * PSTR + ko]);
    __builtin_amdgcn_s_setprio(1);
#pragma unroll
    for (int nt = 0; nt < 8; ++nt) {
      oA[nt] = __builtin_amdgcn_mfma_f32_16x16x32_bf16(pa0, vf[nt], oA[nt], 0, 0, 0);
      oB[nt] = __builtin_amdgcn_mfma_f32_16x16x32_bf16(pa1, vf[nt], oB[nt], 0, 0, 0);
    }
    __builtin_amdgcn_s_setprio(0);
  }

  // ---- lsum reduce: 16-lane shfl -> per-wave slot ----
#pragma unroll
  for (int i = 0; i < 8; ++i) {
    float l = ls[i];
#pragma unroll
    for (int d = 1; d < 16; d <<= 1) l += __shfl_xor(l, d);
    ls[i] = l;
  }
  if (lrow == 0) {
#pragma unroll
    for (int i = 0; i < 8; ++i)
      redl[w][((i >> 2) << 4) + rowb + (i & 3)] = ls[i];
  }
  __syncthreads();  // all P + redl complete
  if (tid < 32) {
    float l = 0.f;
#pragma unroll
    for (int ww = 0; ww < 8; ++ww) l += redl[ww][tid];
    il_s[tid] = 1.0f / l;
  }
  // cross-wave O reduce (k-slice partials)
#pragma unroll
  for (int nt = 0; nt < 8; ++nt)
#pragma unroll
    for (int r = 0; r < 4; ++r) {
      atomicAdd(&obuf[(rowb + r) * 128 + (nt << 4) + lrow], oA[nt][r]);
      atomicAdd(&obuf[(16 + rowb + r) * 128 + (nt << 4) + lrow], oB[nt][r]);
    }
  __syncthreads();  // il_s + obuf complete

  const int orow = tid >> 4;          // 0..31
  const int ocol = (tid & 15) << 3;   // 0..120
  const float ilr = il_s[orow];

  // out = O * il  (coalesced 512B runs)
  {
    float4 u0, u1;
    const float* ob = &obuf[orow * 128 + ocol];
    u0.x = ob[0] * ilr; u0.y = ob[1] * ilr; u0.z = ob[2] * ilr; u0.w = ob[3] * ilr;
    u1.x = ob[4] * ilr; u1.y = ob[5] * ilr; u1.z = ob[6] * ilr; u1.w = ob[7] * ilr;
    float* op = outp + ((size_t)(b * SQ + q0 + orow)) * DD + ocol;
    *(float4*)op = u0;
    *(float4*)(op + 4) = u1;
  }

  // attn = P * il, streamed coalesced + nontemporal
  float* abase = attn + ((size_t)(b * SQ + q0 + orow)) * SK;
  const unsigned short* prow = &P[orow * PSTR];
#pragma unroll 2
  for (int i = 0; i < 16; ++i) {
    const int c0 = (i << 7) + ocol;
    const s16x8 pr = *(const s16x8*)(&prow[c0]);
    f32x4 g0, g1;
    g0[0] = bf2f((unsigned short)pr[0]) * ilr; g0[1] = bf2f((unsigned short)pr[1]) * ilr;
    g0[2] = bf2f((unsigned short)pr[2]) * ilr; g0[3] = bf2f((unsigned short)pr[3]) * ilr;
    g1[0] = bf2f((unsigned short)pr[4]) * ilr; g1[1] = bf2f((unsigned short)pr[5]) * ilr;
    g1[2] = bf2f((unsigned short)pr[6]) * ilr; g1[3] = bf2f((unsigned short)pr[7]) * ilr;
    __builtin_nontemporal_store(g0, (f32x4*)(abase + c0));
    __builtin_nontemporal_store(g1, (f32x4*)(abase + c0 + 4));
  }
}

extern "C" void kernel_launch(void* const* d_in, const int* in_sizes, int n_in,
                              void* d_out, int out_size, void* d_ws, size_t ws_size,
                              hipStream_t stream) {
  const float* q = (const float*)d_in[0];
  const float* k = (const float*)d_in[1];
  const float* v = (const float*)d_in[2];
  const int* mask = (const int*)d_in[3];
  float* outp = (float*)d_out;
  float* attn = outp + (size_t)BB * SQ * DD;

  unsigned short* kb = (unsigned short*)d_ws;
  unsigned short* vt = kb + (size_t)BB * SK * DD;

  prep_k_kernel<<<(BB * SK * DD) / (256 * 8), 256, 0, stream>>>(k, kb);
  prep_v_kernel<<<BB * (SK / 64), 256, 0, stream>>>(v, vt);
  fused_attn<<<BB * (SQ / 32), 512, 0, stream>>>(q, mask, kb, vt, outp, attn);
}